// Round 12
// baseline (228.198 us; speedup 1.0000x reference)
//
#include <hip/hip_runtime.h>
#include <hip/hip_bf16.h>
#include <math.h>

// GNNConv rewrites:
//  (1) msg @ f_w = rel @ f_w[0:3] + x[src] @ f_w[3:]  -> per-node Yb instead of per-edge GEMM
//  (2) fold  z = Zb[s] + qd[d]  where Zb[s]=bf16(Yb[s]+pos[s]@fw3), qd[d]=(delta[d]-pos[d])@fw3
//  (3) MFMA GEMMs with block-level LDS weight staging
//  (4) two-level counting sort: coarse bins of 128 dsts -> LDS multisplit -> half-bin
//      LDS CSR + verified quarter-wave gather (register accumulation, no atomics)
//  (5) r23: aggregate restructuring attempts CLOSED (r18 ILP -7us, r20 chalf -20us,
//      r21 LDS null, r22 quarter-bin -9us) -- the gather is L2-miss queue/latency
//      limited; r19's half-bin structure is the local optimum, frozen. This round:
//      r19-exact + (a) AGG_CAP 2048 (r21-verified equal, less LDS), (b) fw3 reg-hoist
//      in aggregate (r22's one good piece: -24 L1 loads/dst), (c) binsort S3_BATCH
//      4096->8192 isolated (84B runs halve binned write amplification; never isolated
//      before -- r16 bundled it).

typedef __attribute__((ext_vector_type(8))) short bf16x8;
typedef __attribute__((ext_vector_type(4))) float f32x4;

#define LEAKY(v) ((v) >= 0.0f ? (v) : 0.01f * (v))

#define KMAX 512          // max coarse bins (N < 65536 / 128)
#define S3_BATCH 8192     // edges per multisplit block
#define HB 256            // hist blocks inside fused kernel
#define AGG_CAP 2048      // LDS srcs capacity per half-bin (avg ~1024); fallback above

static __device__ __forceinline__ unsigned short f2bf(float f) {
    unsigned u = __float_as_uint(f);
    u = (u + 0x7fffu + ((u >> 16) & 1u)) >> 16;   // RNE
    return (unsigned short)u;
}

union ABu { unsigned short u[8]; bf16x8 v; };

static __device__ __forceinline__ bf16x8 cvt8(const float* __restrict__ p) {
    ABu r;
    const float4 v0 = *(const float4*)p;
    const float4 v1 = *(const float4*)(p + 4);
    r.u[0] = f2bf(v0.x); r.u[1] = f2bf(v0.y); r.u[2] = f2bf(v0.z); r.u[3] = f2bf(v0.w);
    r.u[4] = f2bf(v1.x); r.u[5] = f2bf(v1.y); r.u[6] = f2bf(v1.z); r.u[7] = f2bf(v1.w);
    return r.v;
}

static __device__ __forceinline__ bf16x8 zero_ab() {
    ABu r;
    #pragma unroll
    for (int i = 0; i < 8; ++i) r.u[i] = 0;
    return r.v;
}

// unpack one Zb gather (uint4 = 8 bf16) + fold qd + leaky + accumulate
static __device__ __forceinline__ void proc8(
    const uint4 v, const float* __restrict__ qd, float* __restrict__ acc)
{
    const float f0 = __uint_as_float((v.x & 0xffffu) << 16);
    const float f1 = __uint_as_float(v.x & 0xffff0000u);
    const float f2 = __uint_as_float((v.y & 0xffffu) << 16);
    const float f3 = __uint_as_float(v.y & 0xffff0000u);
    const float f4 = __uint_as_float((v.z & 0xffffu) << 16);
    const float f5 = __uint_as_float(v.z & 0xffff0000u);
    const float f6 = __uint_as_float((v.w & 0xffffu) << 16);
    const float f7 = __uint_as_float(v.w & 0xffff0000u);
    const float z0 = f0 + qd[0], z1 = f1 + qd[1];
    const float z2 = f2 + qd[2], z3 = f3 + qd[3];
    const float z4 = f4 + qd[4], z5 = f5 + qd[5];
    const float z6 = f6 + qd[6], z7 = f7 + qd[7];
    acc[0] += fmaxf(z0, 0.01f * z0);
    acc[1] += fmaxf(z1, 0.01f * z1);
    acc[2] += fmaxf(z2, 0.01f * z2);
    acc[3] += fmaxf(z3, 0.01f * z3);
    acc[4] += fmaxf(z4, 0.01f * z4);
    acc[5] += fmaxf(z5, 0.01f * z5);
    acc[6] += fmaxf(z6, 0.01f * z6);
    acc[7] += fmaxf(z7, 0.01f * z7);
}

// wave-wide inclusive scan (64 lanes)
static __device__ __forceinline__ int wave_incl_scan(int v) {
    const int lane = threadIdx.x & 63;
    #pragma unroll
    for (int d = 1; d < 64; d <<= 1) {
        const int t = __shfl_up(v, d);
        if (lane >= d) v += t;
    }
    return v;
}

// stage a 128x128 bf16 matrix (row-major, stride 128) into LDS [128][136]
static __device__ __forceinline__ void stage_weight(
    const unsigned short* __restrict__ src, unsigned short (*dst)[136], int tid)
{
    #pragma unroll
    for (int it = 0; it < 8; ++it) {
        const int c   = it * 256 + tid;
        const int row = c >> 4;
        const int col = (c & 15) * 8;
        *(uint4*)&dst[row][col] = *(const uint4*)(src + row * 128 + col);
    }
}

// ---------------- weight prep: bf16 transposed copies (W^T[n][k]) + sort-meta zeroing ----
__global__ __launch_bounds__(128) void prep_weights(
    const float* __restrict__ h_w1, const float* __restrict__ f_w,
    const float* __restrict__ g_w1, const float* __restrict__ g_w2,
    unsigned short* __restrict__ Wht, unsigned short* __restrict__ Wft,
    unsigned short* __restrict__ G1t, unsigned short* __restrict__ G2t,
    int* __restrict__ bincnt, int* __restrict__ done)
{
    const int j = blockIdx.x;
    const int k = threadIdx.x;
    if (j == 0) {
        for (int i = k; i < KMAX; i += 128) bincnt[i] = 0;
        if (k == 0) *done = 0;
    }
    Wht[j * 128 + k] = f2bf(h_w1[(size_t)k * 128 + j]);
    Wft[j * 128 + k] = f2bf(f_w[(size_t)(3 + k) * 128 + j]);
    G1t[j * 128 + k] = f2bf(g_w1[(size_t)k * 128 + j]);
    G2t[j * 128 + k] = f2bf(g_w2[(size_t)k * 128 + j]);
}

// ---------------- fused node_pre + coarse_hist ----------------
__global__ __launch_bounds__(256) void fused_pre(
    const float* __restrict__ x, const float* __restrict__ pos,
    const unsigned short* __restrict__ Wht, const float* __restrict__ h_b1,
    const float* __restrict__ h_w2, const float* __restrict__ h_b2,
    const unsigned short* __restrict__ Wft, const float* __restrict__ f_b,
    const float* __restrict__ fw3,     // f_w rows 0..2: [3][128]
    float* __restrict__ deltap, unsigned short* __restrict__ Zb,
    const int* __restrict__ ei, int* __restrict__ bincnt,
    int* __restrict__ binstart, int* __restrict__ cursors,
    int* __restrict__ done, int E, int K, int N)
{
    __shared__ __align__(16) unsigned char smem[34816 + 4096]; // Ws|cb  or  h|s
    __shared__ int lastflag;

    const int tid = threadIdx.x;

    if (blockIdx.x < HB) {
        // ---------------- coarse hist role ----------------
        int* h = (int*)smem;               // [KMAX]
        int* s = (int*)(smem + 2048);      // [256]
        for (int k = tid; k < K; k += 256) h[k] = 0;
        __syncthreads();
        if ((E & 3) == 0) {
            const int E4 = E >> 2;
            const uint4* d4 = (const uint4*)(ei + (size_t)E);
            for (int i = blockIdx.x * 256 + tid; i < E4; i += HB * 256) {
                const uint4 v = d4[i];
                atomicAdd(&h[v.x >> 7], 1);
                atomicAdd(&h[v.y >> 7], 1);
                atomicAdd(&h[v.z >> 7], 1);
                atomicAdd(&h[v.w >> 7], 1);
            }
        } else {
            for (int e = blockIdx.x * 256 + tid; e < E; e += HB * 256)
                atomicAdd(&h[ei[(size_t)E + e] >> 7], 1);
        }
        __syncthreads();
        for (int k = tid; k < K; k += 256) {
            const int v = h[k];
            if (v) atomicAdd(&bincnt[k], v);
        }
        __threadfence();
        __syncthreads();
        if (tid == 0) lastflag = (atomicAdd(done, 1) == HB - 1) ? 1 : 0;
        __syncthreads();
        if (!lastflag) return;

        // scan of K (<= 512) with 256 threads, 2 elements per thread
        const int i0 = tid * 2;
        const int c0 = (i0 < K)     ? atomicAdd(&bincnt[i0], 0)     : 0;
        const int c1 = (i0 + 1 < K) ? atomicAdd(&bincnt[i0 + 1], 0) : 0;
        s[tid] = c0 + c1;
        __syncthreads();
        for (int d = 1; d < 256; d <<= 1) {
            const int t = (tid >= d) ? s[tid - d] : 0;
            __syncthreads();
            s[tid] += t;
            __syncthreads();
        }
        const int ex = s[tid] - (c0 + c1);
        if (i0 < K)     { binstart[i0]     = ex;      cursors[i0]     = ex; }
        if (i0 + 1 < K) { binstart[i0 + 1] = ex + c0; cursors[i0 + 1] = ex + c0; }
        if (tid == 0) binstart[K] = E;
        return;
    }

    // ---------------- node_pre role ----------------
    unsigned short (*Ws)[136] = (unsigned short (*)[136])smem;
    float (*cb)[8] = (float (*)[8])(smem + 34816);

    const int lane = tid & 63;
    const int wave = tid >> 6;
    const int quad = lane >> 4;
    const int l16  = lane & 15;
    const int row0 = (blockIdx.x - HB) * 64 + wave * 16;

    if (tid < 128) {
        cb[tid][0] = h_b1[tid];
        cb[tid][1] = f_b[tid];
        cb[tid][2] = h_w2[tid * 3 + 0];
        cb[tid][3] = h_w2[tid * 3 + 1];
        cb[tid][4] = h_w2[tid * 3 + 2];
        cb[tid][5] = fw3[tid];
        cb[tid][6] = fw3[128 + tid];
        cb[tid][7] = fw3[256 + tid];
    }
    stage_weight(Wht, Ws, tid);

    // A-fragments
    bf16x8 a[4];
    {
        const int row = row0 + l16;
        if (row < N) {
            const float* xp = x + (size_t)row * 128 + quad * 8;
            #pragma unroll
            for (int kc = 0; kc < 4; ++kc) a[kc] = cvt8(xp + kc * 32);
        } else {
            #pragma unroll
            for (int kc = 0; kc < 4; ++kc) a[kc] = zero_ab();
        }
    }

    // pos for this lane's output rows (grow = row0 + quad*4 + reg)
    float px[4], py[4], pz[4];
    #pragma unroll
    for (int reg = 0; reg < 4; ++reg) {
        const int grow = row0 + quad * 4 + reg;
        const int gr = (grow < N) ? grow : 0;
        px[reg] = pos[(size_t)gr * 3 + 0];
        py[reg] = pos[(size_t)gr * 3 + 1];
        pz[reg] = pos[(size_t)gr * 3 + 2];
    }
    __syncthreads();

    // phase 1: acch = x @ h_w1
    f32x4 acch[8];
    #pragma unroll
    for (int nt = 0; nt < 8; ++nt) acch[nt] = (f32x4){0.f, 0.f, 0.f, 0.f};
    #pragma unroll
    for (int nt = 0; nt < 8; ++nt) {
        const unsigned short* wp = &Ws[nt * 16 + l16][quad * 8];
        #pragma unroll
        for (int kc = 0; kc < 4; ++kc) {
            const bf16x8 b = *(const bf16x8*)(wp + kc * 32);
            acch[nt] = __builtin_amdgcn_mfma_f32_16x16x32_bf16(a[kc], b, acch[nt], 0, 0, 0);
        }
    }

    __syncthreads();
    stage_weight(Wft, Ws, tid);
    __syncthreads();

    // phase 2: accf = x @ f_w[3:]
    f32x4 accf[8];
    #pragma unroll
    for (int nt = 0; nt < 8; ++nt) accf[nt] = (f32x4){0.f, 0.f, 0.f, 0.f};
    #pragma unroll
    for (int nt = 0; nt < 8; ++nt) {
        const unsigned short* wp = &Ws[nt * 16 + l16][quad * 8];
        #pragma unroll
        for (int kc = 0; kc < 4; ++kc) {
            const bf16x8 b = *(const bf16x8*)(wp + kc * 32);
            accf[nt] = __builtin_amdgcn_mfma_f32_16x16x32_bf16(a[kc], b, accf[nt], 0, 0, 0);
        }
    }

    // Epilogue. C/D layout: col = nt*16 + l16, local row = quad*4 + reg.
    float p[4][3];
    #pragma unroll
    for (int r = 0; r < 4; ++r) { p[r][0] = 0.f; p[r][1] = 0.f; p[r][2] = 0.f; }

    #pragma unroll
    for (int nt = 0; nt < 8; ++nt) {
        const int col = nt * 16 + l16;
        const float b1  = cb[col][0];
        const float fb  = cb[col][1];
        const float w20 = cb[col][2];
        const float w21 = cb[col][3];
        const float w22 = cb[col][4];
        const float wxc = cb[col][5];
        const float wyc = cb[col][6];
        const float wzc = cb[col][7];
        #pragma unroll
        for (int reg = 0; reg < 4; ++reg) {
            const int grow = row0 + quad * 4 + reg;
            float h = acch[nt][reg] + b1;
            h = LEAKY(h);
            p[reg][0] += h * w20;
            p[reg][1] += h * w21;
            p[reg][2] += h * w22;
            if (grow < N) {
                const float z = accf[nt][reg] + fb
                              + px[reg] * wxc + py[reg] * wyc + pz[reg] * wzc;
                Zb[(size_t)grow * 128 + col] = f2bf(z);
            }
        }
    }

    // reduce p across the 16 l16 lanes (within quad)
    #pragma unroll
    for (int reg = 0; reg < 4; ++reg)
        #pragma unroll
        for (int c = 0; c < 3; ++c) {
            float v = p[reg][c];
            v += __shfl_down(v, 8);
            v += __shfl_down(v, 4);
            v += __shfl_down(v, 2);
            v += __shfl_down(v, 1);
            p[reg][c] = v;
        }

    if (l16 == 0) {
        #pragma unroll
        for (int reg = 0; reg < 4; ++reg) {
            const int grow = row0 + quad * 4 + reg;
            if (grow < N) {
                deltap[(size_t)grow * 3 + 0] = tanhf(p[reg][0] + h_b2[0]) - px[reg];
                deltap[(size_t)grow * 3 + 1] = tanhf(p[reg][1] + h_b2[1]) - py[reg];
                deltap[(size_t)grow * 3 + 2] = tanhf(p[reg][2] + h_b2[2]) - pz[reg];
            }
        }
    }
}

// ---------------- sort stage 3: LDS multisplit into coarse-bin-contiguous records ----
// Per batch: uint4 dst loads -> hist (dsts kept in regs) -> shfl scan -> uint4 src
// loads -> stage[src | dst<<16] -> contiguous run writes of (dst&127)<<16|src.
__global__ __launch_bounds__(512) void binsort(
    const int* __restrict__ ei, int* __restrict__ cursors,
    unsigned int* __restrict__ binned, int E, int K)
{
    __shared__ int h[KMAX];
    __shared__ int hE[KMAX];       // exclusive scan (batch-local bin starts)
    __shared__ int cur[KMAX];      // batch-local placement cursors
    __shared__ int gbase[KMAX];    // global base for this batch's run per bin
    __shared__ int wsum[8];
    __shared__ unsigned int stage[S3_BATCH];   // src | dst<<16 (full dst)

    const int tid = threadIdx.x;
    const int e0  = blockIdx.x * S3_BATCH;
    const int m   = min(S3_BATCH, E - e0);
    const bool vec = (m == S3_BATCH) && ((E & 3) == 0);

    for (int k = tid; k < K; k += 512) h[k] = 0;
    __syncthreads();

    // phase A: load 16 dsts (4 x uint4 per thread)
    unsigned int dsts[16];
    if (vec) {
        const uint4* dv = (const uint4*)(ei + (size_t)E + e0);
        #pragma unroll
        for (int v4 = 0; v4 < 4; ++v4) {
            const uint4 a0 = dv[v4 * 512 + tid];
            dsts[v4 * 4 + 0] = a0.x; dsts[v4 * 4 + 1] = a0.y;
            dsts[v4 * 4 + 2] = a0.z; dsts[v4 * 4 + 3] = a0.w;
        }
        #pragma unroll
        for (int j = 0; j < 16; ++j) atomicAdd(&h[dsts[j] >> 7], 1);
    } else {
        #pragma unroll
        for (int j = 0; j < 16; ++j) {
            const int i = (j >> 2) * (S3_BATCH / 4) + 4 * tid + (j & 3);
            dsts[j] = 0;
            if (i < m) {
                dsts[j] = (unsigned int)ei[(size_t)E + e0 + i];
                atomicAdd(&h[dsts[j] >> 7], 1);
            }
        }
    }
    __syncthreads();

    // scan over K (K <= 512): wave shfl scan + 8 wave sums
    {
        const int c = (tid < K) ? h[tid] : 0;
        int sc = wave_incl_scan(c);
        if ((tid & 63) == 63) wsum[tid >> 6] = sc;
        __syncthreads();
        if (tid < 64) {
            int w = (tid < 8) ? wsum[tid] : 0;
            #pragma unroll
            for (int d = 1; d < 8; d <<= 1) {
                const int t = __shfl_up(w, d);
                if (tid >= d) w += t;
            }
            if (tid < 8) wsum[tid] = w;
        }
        __syncthreads();
        if (tid >= 64) sc += wsum[(tid >> 6) - 1];
        if (tid < K) {
            const int ex = sc - c;
            hE[tid]  = ex;
            cur[tid] = ex;
            gbase[tid] = c ? atomicAdd(&cursors[tid], c) : 0;
        }
    }
    __syncthreads();

    // phase B: load srcs (same edge mapping), place records into LDS sorted by bin
    if (vec) {
        const uint4* sv = (const uint4*)(ei + (size_t)e0);
        #pragma unroll
        for (int v4 = 0; v4 < 4; ++v4) {
            const uint4 b0 = sv[v4 * 512 + tid];
            unsigned int srcs[4] = {b0.x, b0.y, b0.z, b0.w};
            #pragma unroll
            for (int j = 0; j < 4; ++j) {
                const int p = atomicAdd(&cur[dsts[v4 * 4 + j] >> 7], 1);
                stage[p] = srcs[j] | (dsts[v4 * 4 + j] << 16);
            }
        }
    } else {
        #pragma unroll
        for (int j = 0; j < 16; ++j) {
            const int i = (j >> 2) * (S3_BATCH / 4) + 4 * tid + (j & 3);
            if (i < m) {
                const unsigned int src = (unsigned int)ei[(size_t)e0 + i];
                const int p = atomicAdd(&cur[dsts[j] >> 7], 1);
                stage[p] = src | (dsts[j] << 16);
            }
        }
    }
    __syncthreads();

    // phase C: contiguous run writes (consecutive i -> consecutive global addr per bin)
    #pragma unroll
    for (int j = 0; j < S3_BATCH / 512; ++j) {
        const int i = j * 512 + tid;
        if (i < m) {
            const unsigned int r = stage[i];
            const int k = r >> 23;                       // dst >> 7
            binned[(size_t)gbase[k] + (i - hE[k])] = r & 0x007FFFFFu;
        }
    }
}

// ---------------- bin_csr_aggregate: half-bin LDS CSR + verified gather loop ------
// One 512-thread block per (coarse bin x 64-dst half). Prologue: LDS hist + wave
// shfl scan over own 64 dsts, scatter own srcs into LDS (CAP=2048, avg fill ~1024;
// disjoint global fallback windows). Main: 8 waves x 8 dsts; VERIFIED quarter-wave
// gather (unroll-4, ~4 gathers in flight), fw3 hoisted to 24 VGPRs per wave.
__global__ __launch_bounds__(512) void bin_csr_aggregate(
    const unsigned int* __restrict__ binned, const int* __restrict__ binstart,
    const float* __restrict__ deltap,      // [N,3] = delta - pos
    const unsigned short* __restrict__ Zb, // [N,128] bf16
    const float* __restrict__ fw3,         // [3][128]
    unsigned short* __restrict__ srcs_g,   // [E] global fallback scratch
    unsigned short* __restrict__ Ab,       // [N,128] bf16
    int N)
{
    __shared__ int h[64];
    __shared__ int s[64];
    __shared__ int cur[64];
    __shared__ unsigned short sl[AGG_CAP];

    const int tid  = threadIdx.x;
    const int bin  = blockIdx.x >> 1;
    const int half = blockIdx.x & 1;
    const int s0   = binstart[bin];
    const int s1   = binstart[bin + 1];
    const int len  = s1 - s0;

    if (tid < 64) h[tid] = 0;
    __syncthreads();

    // hist over own half's 64 dsts
    for (int i = tid; i < len; i += 512) {
        const int dl16 = binned[(size_t)s0 + i] >> 16;
        if ((dl16 >> 6) == half) atomicAdd(&h[dl16 & 63], 1);
    }
    __syncthreads();

    // inclusive scan of 64 entries: single wave shfl scan
    if (tid < 64) {
        const int hv = h[tid];
        const int sc = wave_incl_scan(hv);
        s[tid]   = sc;
        cur[tid] = sc - hv;
    }
    __syncthreads();

    const int own   = s[63];
    const bool fits = (own <= AGG_CAP);
    const int gb    = half ? (s1 - own) : s0;   // disjoint fallback window base

    // scatter own srcs into LDS (or global scratch on overflow)
    for (int i = tid; i < len; i += 512) {
        const unsigned int r = binned[(size_t)s0 + i];
        const int dl16 = r >> 16;
        if ((dl16 >> 6) == half) {
            const int p = atomicAdd(&cur[dl16 & 63], 1);
            if (fits) sl[p] = (unsigned short)(r & 0xffffu);
            else      srcs_g[(size_t)gb + p] = (unsigned short)(r & 0xffffu);
        }
    }
    __threadfence_block();
    __syncthreads();

    // ---- gather/aggregate (verified r2/r16 structure) ----
    const int lane    = tid & 63;
    const int wv      = tid >> 6;          // 8 waves
    const int quarter = lane >> 4;
    const int cl      = (lane & 15) * 8;
    const int d0      = bin * 128 + half * 64;

    // fw3 hoisted once per wave (was 24 L1 loads per dst)
    float fx[8], fy[8], fz[8];
    #pragma unroll
    for (int j = 0; j < 8; ++j) {
        fx[j] = fw3[cl + j];
        fy[j] = fw3[128 + cl + j];
        fz[j] = fw3[256 + cl + j];
    }

    for (int dl = wv; dl < 64; dl += 8) {
        const int d = d0 + dl;
        if (d >= N) continue;

        const int len_d = h[dl];
        const int start = s[dl] - h[dl];   // local offset within own half

        const float q0 = deltap[(size_t)d * 3 + 0];
        const float q1 = deltap[(size_t)d * 3 + 1];
        const float q2 = deltap[(size_t)d * 3 + 2];

        float qd[8];
        #pragma unroll
        for (int j = 0; j < 8; ++j)
            qd[j] = q0 * fx[j] + q1 * fy[j] + q2 * fz[j];

        float acc[8] = {0.f, 0.f, 0.f, 0.f, 0.f, 0.f, 0.f, 0.f};

        for (int chunk = 0; chunk < len_d; chunk += 64) {
            const int m = min(64, len_d - chunk);
            int idx = 0;
            if (lane < m)
                idx = fits ? (int)sl[start + chunk + lane]
                           : (int)srcs_g[(size_t)gb + start + chunk + lane];

            int t = 0;
            #pragma unroll 4
            for (; t + 4 <= m; t += 4) {
                const int sidx = __shfl(idx, t + quarter);
                const uint4 y = *(const uint4*)(Zb + (size_t)sidx * 128 + cl);
                proc8(y, qd, acc);
            }
            if (t < m) {   // tail: up to 3 edges, predicated per-quarter
                const int e = t + quarter;       // <= 63 always
                const int sidx = __shfl(idx, e);
                if (e < m) {
                    const uint4 y = *(const uint4*)(Zb + (size_t)sidx * 128 + cl);
                    proc8(y, qd, acc);
                }
            }
        }

        #pragma unroll
        for (int j = 0; j < 8; ++j) {
            acc[j] += __shfl_xor(acc[j], 16);
            acc[j] += __shfl_xor(acc[j], 32);
        }
        if (quarter == 0) {
            ABu o;
            #pragma unroll
            for (int j = 0; j < 8; ++j) o.u[j] = f2bf(acc[j]);
            *(bf16x8*)(Ab + (size_t)d * 128 + cl) = o.v;
        }
    }
}

// ---------------- gemm_g (MFMA, LDS-staged weights): out = leaky(Ab@g_w1+b1)@g_w2+b2+x ----
__global__ __launch_bounds__(256) void gemm_g(
    const unsigned short* __restrict__ Ab,   // [N,128] bf16
    const unsigned short* __restrict__ G1t, const float* __restrict__ g_b1,
    const unsigned short* __restrict__ G2t, const float* __restrict__ g_b2,
    const float* __restrict__ x,
    float* __restrict__ out, int N)
{
    __shared__ unsigned short Ws[128][136];
    __shared__ unsigned short Ts[64][136];

    const int tid  = threadIdx.x;
    const int lane = tid & 63;
    const int wave = tid >> 6;
    const int quad = lane >> 4;
    const int l16  = lane & 15;
    const int row0 = blockIdx.x * 64 + wave * 16;

    stage_weight(G1t, Ws, tid);

    bf16x8 a[4];
    {
        const int row = row0 + l16;
        if (row < N) {
            const unsigned short* ap = Ab + (size_t)row * 128 + quad * 8;
            #pragma unroll
            for (int kc = 0; kc < 4; ++kc) a[kc] = *(const bf16x8*)(ap + kc * 32);
        } else {
            #pragma unroll
            for (int kc = 0; kc < 4; ++kc) a[kc] = zero_ab();
        }
    }
    __syncthreads();

    f32x4 acc[8];
    #pragma unroll
    for (int nt = 0; nt < 8; ++nt) acc[nt] = (f32x4){0.f, 0.f, 0.f, 0.f};
    #pragma unroll
    for (int nt = 0; nt < 8; ++nt) {
        const unsigned short* wp = &Ws[nt * 16 + l16][quad * 8];
        #pragma unroll
        for (int kc = 0; kc < 4; ++kc) {
            const bf16x8 b = *(const bf16x8*)(wp + kc * 32);
            acc[nt] = __builtin_amdgcn_mfma_f32_16x16x32_bf16(a[kc], b, acc[nt], 0, 0, 0);
        }
    }

    #pragma unroll
    for (int nt = 0; nt < 8; ++nt) {
        const int col = nt * 16 + l16;
        const float b1 = g_b1[col];
        #pragma unroll
        for (int reg = 0; reg < 4; ++reg) {
            float t = acc[nt][reg] + b1;
            t = LEAKY(t);
            Ts[wave * 16 + quad * 4 + reg][col] = f2bf(t);
        }
    }
    __syncthreads();
    stage_weight(G2t, Ws, tid);
    __syncthreads();

    bf16x8 a2[4];
    {
        const unsigned short* tp = &Ts[wave * 16 + l16][quad * 8];
        #pragma unroll
        for (int kc = 0; kc < 4; ++kc) a2[kc] = *(const bf16x8*)(tp + kc * 32);
    }

    f32x4 acc2[8];
    #pragma unroll
    for (int nt = 0; nt < 8; ++nt) acc2[nt] = (f32x4){0.f, 0.f, 0.f, 0.f};
    #pragma unroll
    for (int nt = 0; nt < 8; ++nt) {
        const unsigned short* wp = &Ws[nt * 16 + l16][quad * 8];
        #pragma unroll
        for (int kc = 0; kc < 4; ++kc) {
            const bf16x8 b = *(const bf16x8*)(wp + kc * 32);
            acc2[nt] = __builtin_amdgcn_mfma_f32_16x16x32_bf16(a2[kc], b, acc2[nt], 0, 0, 0);
        }
    }

    #pragma unroll
    for (int nt = 0; nt < 8; ++nt) {
        const int col = nt * 16 + l16;
        const float b2 = g_b2[col];
        #pragma unroll
        for (int reg = 0; reg < 4; ++reg) {
            const int grow = row0 + quad * 4 + reg;
            if (grow < N)
                out[(size_t)grow * 128 + col] =
                    acc2[nt][reg] + b2 + x[(size_t)grow * 128 + col];
        }
    }
}

// ---------------- launch ----------------
extern "C" void kernel_launch(void* const* d_in, const int* in_sizes, int n_in,
                              void* d_out, int out_size, void* d_ws, size_t ws_size,
                              hipStream_t stream) {
    const float* x    = (const float*)d_in[0];
    const float* pos  = (const float*)d_in[1];
    const int*   ei   = (const int*)d_in[2];
    const float* h_w1 = (const float*)d_in[3];
    const float* h_b1 = (const float*)d_in[4];
    const float* h_w2 = (const float*)d_in[5];
    const float* h_b2 = (const float*)d_in[6];
    const float* f_w  = (const float*)d_in[7];   // [131,128]
    const float* f_b  = (const float*)d_in[8];
    const float* g_w1 = (const float*)d_in[9];
    const float* g_b1 = (const float*)d_in[10];
    const float* g_w2 = (const float*)d_in[11];
    const float* g_b2 = (const float*)d_in[12];
    float* out = (float*)d_out;

    const int N = in_sizes[0] / 128;
    const int E = in_sizes[2] / 2;
    const int K = (N + 127) >> 7;          // coarse bins (128 dsts each), K <= KMAX

    // ws (~32 MB of 256 MB): deltap[N*3]f32 | Zb[N*128]u16 | bincnt[KMAX] |
    //   binstart[KMAX+1] | cursors[KMAX] | done | binned[E]u32 | srcs[E]u16 (fallback) |
    //   Wht/Wft/G1t/G2t [128*128]u16 each | Ab[N*128]u16
    float* deltap         = (float*)d_ws;
    unsigned short* Zb    = (unsigned short*)(deltap + (size_t)N * 3);
    int* bincnt           = (int*)(Zb + (size_t)N * 128);
    int* binstart         = bincnt + KMAX;
    int* cursors          = binstart + (KMAX + 1);
    int* done             = cursors + KMAX;
    unsigned int* binned  = (unsigned int*)(done + 1);
    unsigned short* srcs  = (unsigned short*)(binned + E);
    unsigned short* Wht   = srcs + (((size_t)E + 1) & ~(size_t)1);
    unsigned short* Wft   = Wht + 128 * 128;
    unsigned short* G1t   = Wft + 128 * 128;
    unsigned short* G2t   = G1t + 128 * 128;
    unsigned short* Ab    = G2t + 128 * 128;

    const int tile_blocks = (N + 63) / 64;
    const int sort_blocks = (E + S3_BATCH - 1) / S3_BATCH;

    prep_weights<<<128, 128, 0, stream>>>(h_w1, f_w, g_w1, g_w2, Wht, Wft, G1t, G2t,
                                          bincnt, done);

    fused_pre<<<HB + tile_blocks, 256, 0, stream>>>(
        x, pos, Wht, h_b1, h_w2, h_b2, Wft, f_b, f_w,
        deltap, Zb, ei, bincnt, binstart, cursors, done, E, K, N);

    binsort<<<sort_blocks, 512, 0, stream>>>(ei, cursors, binned, E, K);

    bin_csr_aggregate<<<K * 2, 512, 0, stream>>>(binned, binstart, deltap, Zb, f_w,
                                                 srcs, Ab, N);

    gemm_g<<<tile_blocks, 256, 0, stream>>>(Ab, G1t, g_b1, G2t, g_b2, x, out, N);
}

// Round 13
// 215.618 us; speedup vs baseline: 1.0583x; 1.0583x over previous
//
#include <hip/hip_runtime.h>
#include <hip/hip_bf16.h>
#include <math.h>

// GNNConv rewrites:
//  (1) msg @ f_w = rel @ f_w[0:3] + x[src] @ f_w[3:]  -> per-node Yb instead of per-edge GEMM
//  (2) fold  z = Zb[s] + qd[d]  where Zb[s]=bf16(Yb[s]+pos[s]@fw3), qd[d]=(delta[d]-pos[d])@fw3
//  (3) MFMA GEMMs with block-level LDS weight staging
//  (4) two-level counting sort: coarse bins of 128 dsts -> LDS multisplit -> half-bin
//      LDS CSR + verified quarter-wave gather (register accumulation, no atomics)
//  (5) r24: EXACT REVERT to r19 (best measured: 217.08us). Closed experiments on the
//      aggregate gather: r18 manual ILP +10us, r20 chalf+XCD +20us, r21 LDS-shrink null,
//      r22 quarter-bin +9us, r23 fw3-reg-hoist +13us (VGPR 32->40 perturbed the
//      compiler's schedule; Occ 44->33). The unroll-4 VGPR-32 gather is the optimum --
//      L2-miss-latency-limited at ~46us / 106MB FETCH (8x Zb per-XCD refetch floor).

typedef __attribute__((ext_vector_type(8))) short bf16x8;
typedef __attribute__((ext_vector_type(4))) float f32x4;

#define LEAKY(v) ((v) >= 0.0f ? (v) : 0.01f * (v))

#define KMAX 512          // max coarse bins (N < 65536 / 128)
#define S3_BATCH 4096     // edges per multisplit block
#define HB 256            // hist blocks inside fused kernel
#define AGG_CAP 16384     // LDS srcs capacity per half-bin; global fallback above

static __device__ __forceinline__ unsigned short f2bf(float f) {
    unsigned u = __float_as_uint(f);
    u = (u + 0x7fffu + ((u >> 16) & 1u)) >> 16;   // RNE
    return (unsigned short)u;
}

union ABu { unsigned short u[8]; bf16x8 v; };

static __device__ __forceinline__ bf16x8 cvt8(const float* __restrict__ p) {
    ABu r;
    const float4 v0 = *(const float4*)p;
    const float4 v1 = *(const float4*)(p + 4);
    r.u[0] = f2bf(v0.x); r.u[1] = f2bf(v0.y); r.u[2] = f2bf(v0.z); r.u[3] = f2bf(v0.w);
    r.u[4] = f2bf(v1.x); r.u[5] = f2bf(v1.y); r.u[6] = f2bf(v1.z); r.u[7] = f2bf(v1.w);
    return r.v;
}

static __device__ __forceinline__ bf16x8 zero_ab() {
    ABu r;
    #pragma unroll
    for (int i = 0; i < 8; ++i) r.u[i] = 0;
    return r.v;
}

// unpack one Zb gather (uint4 = 8 bf16) + fold qd + leaky + accumulate
static __device__ __forceinline__ void proc8(
    const uint4 v, const float* __restrict__ qd, float* __restrict__ acc)
{
    const float f0 = __uint_as_float((v.x & 0xffffu) << 16);
    const float f1 = __uint_as_float(v.x & 0xffff0000u);
    const float f2 = __uint_as_float((v.y & 0xffffu) << 16);
    const float f3 = __uint_as_float(v.y & 0xffff0000u);
    const float f4 = __uint_as_float((v.z & 0xffffu) << 16);
    const float f5 = __uint_as_float(v.z & 0xffff0000u);
    const float f6 = __uint_as_float((v.w & 0xffffu) << 16);
    const float f7 = __uint_as_float(v.w & 0xffff0000u);
    const float z0 = f0 + qd[0], z1 = f1 + qd[1];
    const float z2 = f2 + qd[2], z3 = f3 + qd[3];
    const float z4 = f4 + qd[4], z5 = f5 + qd[5];
    const float z6 = f6 + qd[6], z7 = f7 + qd[7];
    acc[0] += fmaxf(z0, 0.01f * z0);
    acc[1] += fmaxf(z1, 0.01f * z1);
    acc[2] += fmaxf(z2, 0.01f * z2);
    acc[3] += fmaxf(z3, 0.01f * z3);
    acc[4] += fmaxf(z4, 0.01f * z4);
    acc[5] += fmaxf(z5, 0.01f * z5);
    acc[6] += fmaxf(z6, 0.01f * z6);
    acc[7] += fmaxf(z7, 0.01f * z7);
}

// wave-wide inclusive scan (64 lanes)
static __device__ __forceinline__ int wave_incl_scan(int v) {
    const int lane = threadIdx.x & 63;
    #pragma unroll
    for (int d = 1; d < 64; d <<= 1) {
        const int t = __shfl_up(v, d);
        if (lane >= d) v += t;
    }
    return v;
}

// stage a 128x128 bf16 matrix (row-major, stride 128) into LDS [128][136]
static __device__ __forceinline__ void stage_weight(
    const unsigned short* __restrict__ src, unsigned short (*dst)[136], int tid)
{
    #pragma unroll
    for (int it = 0; it < 8; ++it) {
        const int c   = it * 256 + tid;
        const int row = c >> 4;
        const int col = (c & 15) * 8;
        *(uint4*)&dst[row][col] = *(const uint4*)(src + row * 128 + col);
    }
}

// ---------------- weight prep: bf16 transposed copies (W^T[n][k]) + sort-meta zeroing ----
__global__ __launch_bounds__(128) void prep_weights(
    const float* __restrict__ h_w1, const float* __restrict__ f_w,
    const float* __restrict__ g_w1, const float* __restrict__ g_w2,
    unsigned short* __restrict__ Wht, unsigned short* __restrict__ Wft,
    unsigned short* __restrict__ G1t, unsigned short* __restrict__ G2t,
    int* __restrict__ bincnt, int* __restrict__ done)
{
    const int j = blockIdx.x;
    const int k = threadIdx.x;
    if (j == 0) {
        for (int i = k; i < KMAX; i += 128) bincnt[i] = 0;
        if (k == 0) *done = 0;
    }
    Wht[j * 128 + k] = f2bf(h_w1[(size_t)k * 128 + j]);
    Wft[j * 128 + k] = f2bf(f_w[(size_t)(3 + k) * 128 + j]);
    G1t[j * 128 + k] = f2bf(g_w1[(size_t)k * 128 + j]);
    G2t[j * 128 + k] = f2bf(g_w2[(size_t)k * 128 + j]);
}

// ---------------- fused node_pre + coarse_hist ----------------
__global__ __launch_bounds__(256) void fused_pre(
    const float* __restrict__ x, const float* __restrict__ pos,
    const unsigned short* __restrict__ Wht, const float* __restrict__ h_b1,
    const float* __restrict__ h_w2, const float* __restrict__ h_b2,
    const unsigned short* __restrict__ Wft, const float* __restrict__ f_b,
    const float* __restrict__ fw3,     // f_w rows 0..2: [3][128]
    float* __restrict__ deltap, unsigned short* __restrict__ Zb,
    const int* __restrict__ ei, int* __restrict__ bincnt,
    int* __restrict__ binstart, int* __restrict__ cursors,
    int* __restrict__ done, int E, int K, int N)
{
    __shared__ __align__(16) unsigned char smem[34816 + 4096]; // Ws|cb  or  h|s
    __shared__ int lastflag;

    const int tid = threadIdx.x;

    if (blockIdx.x < HB) {
        // ---------------- coarse hist role ----------------
        int* h = (int*)smem;               // [KMAX]
        int* s = (int*)(smem + 2048);      // [256]
        for (int k = tid; k < K; k += 256) h[k] = 0;
        __syncthreads();
        if ((E & 3) == 0) {
            const int E4 = E >> 2;
            const uint4* d4 = (const uint4*)(ei + (size_t)E);
            for (int i = blockIdx.x * 256 + tid; i < E4; i += HB * 256) {
                const uint4 v = d4[i];
                atomicAdd(&h[v.x >> 7], 1);
                atomicAdd(&h[v.y >> 7], 1);
                atomicAdd(&h[v.z >> 7], 1);
                atomicAdd(&h[v.w >> 7], 1);
            }
        } else {
            for (int e = blockIdx.x * 256 + tid; e < E; e += HB * 256)
                atomicAdd(&h[ei[(size_t)E + e] >> 7], 1);
        }
        __syncthreads();
        for (int k = tid; k < K; k += 256) {
            const int v = h[k];
            if (v) atomicAdd(&bincnt[k], v);
        }
        __threadfence();
        __syncthreads();
        if (tid == 0) lastflag = (atomicAdd(done, 1) == HB - 1) ? 1 : 0;
        __syncthreads();
        if (!lastflag) return;

        // scan of K (<= 512) with 256 threads, 2 elements per thread
        const int i0 = tid * 2;
        const int c0 = (i0 < K)     ? atomicAdd(&bincnt[i0], 0)     : 0;
        const int c1 = (i0 + 1 < K) ? atomicAdd(&bincnt[i0 + 1], 0) : 0;
        s[tid] = c0 + c1;
        __syncthreads();
        for (int d = 1; d < 256; d <<= 1) {
            const int t = (tid >= d) ? s[tid - d] : 0;
            __syncthreads();
            s[tid] += t;
            __syncthreads();
        }
        const int ex = s[tid] - (c0 + c1);
        if (i0 < K)     { binstart[i0]     = ex;      cursors[i0]     = ex; }
        if (i0 + 1 < K) { binstart[i0 + 1] = ex + c0; cursors[i0 + 1] = ex + c0; }
        if (tid == 0) binstart[K] = E;
        return;
    }

    // ---------------- node_pre role ----------------
    unsigned short (*Ws)[136] = (unsigned short (*)[136])smem;
    float (*cb)[8] = (float (*)[8])(smem + 34816);

    const int lane = tid & 63;
    const int wave = tid >> 6;
    const int quad = lane >> 4;
    const int l16  = lane & 15;
    const int row0 = (blockIdx.x - HB) * 64 + wave * 16;

    if (tid < 128) {
        cb[tid][0] = h_b1[tid];
        cb[tid][1] = f_b[tid];
        cb[tid][2] = h_w2[tid * 3 + 0];
        cb[tid][3] = h_w2[tid * 3 + 1];
        cb[tid][4] = h_w2[tid * 3 + 2];
        cb[tid][5] = fw3[tid];
        cb[tid][6] = fw3[128 + tid];
        cb[tid][7] = fw3[256 + tid];
    }
    stage_weight(Wht, Ws, tid);

    // A-fragments
    bf16x8 a[4];
    {
        const int row = row0 + l16;
        if (row < N) {
            const float* xp = x + (size_t)row * 128 + quad * 8;
            #pragma unroll
            for (int kc = 0; kc < 4; ++kc) a[kc] = cvt8(xp + kc * 32);
        } else {
            #pragma unroll
            for (int kc = 0; kc < 4; ++kc) a[kc] = zero_ab();
        }
    }

    // pos for this lane's output rows (grow = row0 + quad*4 + reg)
    float px[4], py[4], pz[4];
    #pragma unroll
    for (int reg = 0; reg < 4; ++reg) {
        const int grow = row0 + quad * 4 + reg;
        const int gr = (grow < N) ? grow : 0;
        px[reg] = pos[(size_t)gr * 3 + 0];
        py[reg] = pos[(size_t)gr * 3 + 1];
        pz[reg] = pos[(size_t)gr * 3 + 2];
    }
    __syncthreads();

    // phase 1: acch = x @ h_w1
    f32x4 acch[8];
    #pragma unroll
    for (int nt = 0; nt < 8; ++nt) acch[nt] = (f32x4){0.f, 0.f, 0.f, 0.f};
    #pragma unroll
    for (int nt = 0; nt < 8; ++nt) {
        const unsigned short* wp = &Ws[nt * 16 + l16][quad * 8];
        #pragma unroll
        for (int kc = 0; kc < 4; ++kc) {
            const bf16x8 b = *(const bf16x8*)(wp + kc * 32);
            acch[nt] = __builtin_amdgcn_mfma_f32_16x16x32_bf16(a[kc], b, acch[nt], 0, 0, 0);
        }
    }

    __syncthreads();
    stage_weight(Wft, Ws, tid);
    __syncthreads();

    // phase 2: accf = x @ f_w[3:]
    f32x4 accf[8];
    #pragma unroll
    for (int nt = 0; nt < 8; ++nt) accf[nt] = (f32x4){0.f, 0.f, 0.f, 0.f};
    #pragma unroll
    for (int nt = 0; nt < 8; ++nt) {
        const unsigned short* wp = &Ws[nt * 16 + l16][quad * 8];
        #pragma unroll
        for (int kc = 0; kc < 4; ++kc) {
            const bf16x8 b = *(const bf16x8*)(wp + kc * 32);
            accf[nt] = __builtin_amdgcn_mfma_f32_16x16x32_bf16(a[kc], b, accf[nt], 0, 0, 0);
        }
    }

    // Epilogue. C/D layout: col = nt*16 + l16, local row = quad*4 + reg.
    float p[4][3];
    #pragma unroll
    for (int r = 0; r < 4; ++r) { p[r][0] = 0.f; p[r][1] = 0.f; p[r][2] = 0.f; }

    #pragma unroll
    for (int nt = 0; nt < 8; ++nt) {
        const int col = nt * 16 + l16;
        const float b1  = cb[col][0];
        const float fb  = cb[col][1];
        const float w20 = cb[col][2];
        const float w21 = cb[col][3];
        const float w22 = cb[col][4];
        const float wxc = cb[col][5];
        const float wyc = cb[col][6];
        const float wzc = cb[col][7];
        #pragma unroll
        for (int reg = 0; reg < 4; ++reg) {
            const int grow = row0 + quad * 4 + reg;
            float h = acch[nt][reg] + b1;
            h = LEAKY(h);
            p[reg][0] += h * w20;
            p[reg][1] += h * w21;
            p[reg][2] += h * w22;
            if (grow < N) {
                const float z = accf[nt][reg] + fb
                              + px[reg] * wxc + py[reg] * wyc + pz[reg] * wzc;
                Zb[(size_t)grow * 128 + col] = f2bf(z);
            }
        }
    }

    // reduce p across the 16 l16 lanes (within quad)
    #pragma unroll
    for (int reg = 0; reg < 4; ++reg)
        #pragma unroll
        for (int c = 0; c < 3; ++c) {
            float v = p[reg][c];
            v += __shfl_down(v, 8);
            v += __shfl_down(v, 4);
            v += __shfl_down(v, 2);
            v += __shfl_down(v, 1);
            p[reg][c] = v;
        }

    if (l16 == 0) {
        #pragma unroll
        for (int reg = 0; reg < 4; ++reg) {
            const int grow = row0 + quad * 4 + reg;
            if (grow < N) {
                deltap[(size_t)grow * 3 + 0] = tanhf(p[reg][0] + h_b2[0]) - px[reg];
                deltap[(size_t)grow * 3 + 1] = tanhf(p[reg][1] + h_b2[1]) - py[reg];
                deltap[(size_t)grow * 3 + 2] = tanhf(p[reg][2] + h_b2[2]) - pz[reg];
            }
        }
    }
}

// ---------------- sort stage 3: LDS multisplit into coarse-bin-contiguous records ----
// Per batch: uint4 dst loads -> hist (dsts kept in regs) -> shfl scan -> uint4 src
// loads -> stage[src | dst<<16] -> contiguous run writes of (dst&127)<<16|src.
__global__ __launch_bounds__(512) void binsort(
    const int* __restrict__ ei, int* __restrict__ cursors,
    unsigned int* __restrict__ binned, int E, int K)
{
    __shared__ int h[KMAX];
    __shared__ int hE[KMAX];       // exclusive scan (batch-local bin starts)
    __shared__ int cur[KMAX];      // batch-local placement cursors
    __shared__ int gbase[KMAX];    // global base for this batch's run per bin
    __shared__ int wsum[8];
    __shared__ unsigned int stage[S3_BATCH];   // src | dst<<16 (full dst)

    const int tid = threadIdx.x;
    const int e0  = blockIdx.x * S3_BATCH;
    const int m   = min(S3_BATCH, E - e0);
    const bool vec = (m == S3_BATCH) && ((E & 3) == 0);

    for (int k = tid; k < K; k += 512) h[k] = 0;
    __syncthreads();

    // phase A: load 8 dsts (edge idx: j<4 -> 4*tid+j ; else S3_BATCH/2 + 4*tid + j-4)
    unsigned int dsts[8];
    if (vec) {
        const uint4* dv = (const uint4*)(ei + (size_t)E + e0);
        const uint4 a0 = dv[tid];
        const uint4 a1 = dv[tid + 512];
        dsts[0] = a0.x; dsts[1] = a0.y; dsts[2] = a0.z; dsts[3] = a0.w;
        dsts[4] = a1.x; dsts[5] = a1.y; dsts[6] = a1.z; dsts[7] = a1.w;
        #pragma unroll
        for (int j = 0; j < 8; ++j) atomicAdd(&h[dsts[j] >> 7], 1);
    } else {
        #pragma unroll
        for (int j = 0; j < 8; ++j) {
            const int i = (j < 4) ? (4 * tid + j) : (S3_BATCH / 2 + 4 * tid + j - 4);
            dsts[j] = 0;
            if (i < m) {
                dsts[j] = (unsigned int)ei[(size_t)E + e0 + i];
                atomicAdd(&h[dsts[j] >> 7], 1);
            }
        }
    }
    __syncthreads();

    // scan over K (K <= 512): wave shfl scan + 8 wave sums
    {
        const int c = (tid < K) ? h[tid] : 0;
        int sc = wave_incl_scan(c);
        if ((tid & 63) == 63) wsum[tid >> 6] = sc;
        __syncthreads();
        if (tid < 64) {
            int w = (tid < 8) ? wsum[tid] : 0;
            #pragma unroll
            for (int d = 1; d < 8; d <<= 1) {
                const int t = __shfl_up(w, d);
                if (tid >= d) w += t;
            }
            if (tid < 8) wsum[tid] = w;
        }
        __syncthreads();
        if (tid >= 64) sc += wsum[(tid >> 6) - 1];
        if (tid < K) {
            const int ex = sc - c;
            hE[tid]  = ex;
            cur[tid] = ex;
            gbase[tid] = c ? atomicAdd(&cursors[tid], c) : 0;
        }
    }
    __syncthreads();

    // phase B: load srcs (same edge mapping), place records into LDS sorted by bin
    if (vec) {
        const uint4* sv = (const uint4*)(ei + (size_t)e0);
        const uint4 b0 = sv[tid];
        const uint4 b1 = sv[tid + 512];
        unsigned int srcs[8];
        srcs[0] = b0.x; srcs[1] = b0.y; srcs[2] = b0.z; srcs[3] = b0.w;
        srcs[4] = b1.x; srcs[5] = b1.y; srcs[6] = b1.z; srcs[7] = b1.w;
        #pragma unroll
        for (int j = 0; j < 8; ++j) {
            const int p = atomicAdd(&cur[dsts[j] >> 7], 1);
            stage[p] = srcs[j] | (dsts[j] << 16);
        }
    } else {
        #pragma unroll
        for (int j = 0; j < 8; ++j) {
            const int i = (j < 4) ? (4 * tid + j) : (S3_BATCH / 2 + 4 * tid + j - 4);
            if (i < m) {
                const unsigned int src = (unsigned int)ei[(size_t)e0 + i];
                const int p = atomicAdd(&cur[dsts[j] >> 7], 1);
                stage[p] = src | (dsts[j] << 16);
            }
        }
    }
    __syncthreads();

    // phase C: contiguous run writes (consecutive i -> consecutive global addr per bin)
    #pragma unroll
    for (int j = 0; j < S3_BATCH / 512; ++j) {
        const int i = j * 512 + tid;
        if (i < m) {
            const unsigned int r = stage[i];
            const int k = r >> 23;                       // dst >> 7
            binned[(size_t)gbase[k] + (i - hE[k])] = r & 0x007FFFFFu;
        }
    }
}

// ---------------- bin_csr_aggregate: half-bin LDS CSR + verified gather loop ------
// One 512-thread block per (coarse bin x 64-dst half). Prologue: LDS hist + wave
// shfl scan over own 64 dsts, scatter own srcs into LDS (CAP=16K; disjoint global
// fallback windows). Main: 8 waves x 8 dsts; VERIFIED quarter-wave gather (unroll-4,
// ~4 gathers in flight), register accumulation, no atomics.
__global__ __launch_bounds__(512) void bin_csr_aggregate(
    const unsigned int* __restrict__ binned, const int* __restrict__ binstart,
    const float* __restrict__ deltap,      // [N,3] = delta - pos
    const unsigned short* __restrict__ Zb, // [N,128] bf16
    const float* __restrict__ fw3,         // [3][128]
    unsigned short* __restrict__ srcs_g,   // [E] global fallback scratch
    unsigned short* __restrict__ Ab,       // [N,128] bf16
    int N)
{
    __shared__ int h[64];
    __shared__ int s[64];
    __shared__ int cur[64];
    __shared__ unsigned short sl[AGG_CAP];

    const int tid  = threadIdx.x;
    const int bin  = blockIdx.x >> 1;
    const int half = blockIdx.x & 1;
    const int s0   = binstart[bin];
    const int s1   = binstart[bin + 1];
    const int len  = s1 - s0;

    if (tid < 64) h[tid] = 0;
    __syncthreads();

    // hist over own half's 64 dsts
    for (int i = tid; i < len; i += 512) {
        const int dl16 = binned[(size_t)s0 + i] >> 16;
        if ((dl16 >> 6) == half) atomicAdd(&h[dl16 & 63], 1);
    }
    __syncthreads();

    // inclusive scan of 64 entries: single wave shfl scan
    if (tid < 64) {
        const int hv = h[tid];
        const int sc = wave_incl_scan(hv);
        s[tid]   = sc;
        cur[tid] = sc - hv;
    }
    __syncthreads();

    const int own   = s[63];
    const bool fits = (own <= AGG_CAP);
    const int gb    = half ? (s1 - own) : s0;   // disjoint fallback window base

    // scatter own srcs into LDS (or global scratch on overflow)
    for (int i = tid; i < len; i += 512) {
        const unsigned int r = binned[(size_t)s0 + i];
        const int dl16 = r >> 16;
        if ((dl16 >> 6) == half) {
            const int p = atomicAdd(&cur[dl16 & 63], 1);
            if (fits) sl[p] = (unsigned short)(r & 0xffffu);
            else      srcs_g[(size_t)gb + p] = (unsigned short)(r & 0xffffu);
        }
    }
    __threadfence_block();
    __syncthreads();

    // ---- gather/aggregate (verified r2/r16 structure) ----
    const int lane    = tid & 63;
    const int wv      = tid >> 6;          // 8 waves
    const int quarter = lane >> 4;
    const int cl      = (lane & 15) * 8;
    const int d0      = bin * 128 + half * 64;

    for (int dl = wv; dl < 64; dl += 8) {
        const int d = d0 + dl;
        if (d >= N) continue;

        const int len_d = h[dl];
        const int start = s[dl] - h[dl];   // local offset within own half

        const float q0 = deltap[(size_t)d * 3 + 0];
        const float q1 = deltap[(size_t)d * 3 + 1];
        const float q2 = deltap[(size_t)d * 3 + 2];

        float qd[8];
        #pragma unroll
        for (int j = 0; j < 8; ++j)
            qd[j] = q0 * fw3[cl + j] + q1 * fw3[128 + cl + j] + q2 * fw3[256 + cl + j];

        float acc[8] = {0.f, 0.f, 0.f, 0.f, 0.f, 0.f, 0.f, 0.f};

        for (int chunk = 0; chunk < len_d; chunk += 64) {
            const int m = min(64, len_d - chunk);
            int idx = 0;
            if (lane < m)
                idx = fits ? (int)sl[start + chunk + lane]
                           : (int)srcs_g[(size_t)gb + start + chunk + lane];

            int t = 0;
            #pragma unroll 4
            for (; t + 4 <= m; t += 4) {
                const int sidx = __shfl(idx, t + quarter);
                const uint4 y = *(const uint4*)(Zb + (size_t)sidx * 128 + cl);
                proc8(y, qd, acc);
            }
            if (t < m) {   // tail: up to 3 edges, predicated per-quarter
                const int e = t + quarter;       // <= 63 always
                const int sidx = __shfl(idx, e);
                if (e < m) {
                    const uint4 y = *(const uint4*)(Zb + (size_t)sidx * 128 + cl);
                    proc8(y, qd, acc);
                }
            }
        }

        #pragma unroll
        for (int j = 0; j < 8; ++j) {
            acc[j] += __shfl_xor(acc[j], 16);
            acc[j] += __shfl_xor(acc[j], 32);
        }
        if (quarter == 0) {
            ABu o;
            #pragma unroll
            for (int j = 0; j < 8; ++j) o.u[j] = f2bf(acc[j]);
            *(bf16x8*)(Ab + (size_t)d * 128 + cl) = o.v;
        }
    }
}

// ---------------- gemm_g (MFMA, LDS-staged weights): out = leaky(Ab@g_w1+b1)@g_w2+b2+x ----
__global__ __launch_bounds__(256) void gemm_g(
    const unsigned short* __restrict__ Ab,   // [N,128] bf16
    const unsigned short* __restrict__ G1t, const float* __restrict__ g_b1,
    const unsigned short* __restrict__ G2t, const float* __restrict__ g_b2,
    const float* __restrict__ x,
    float* __restrict__ out, int N)
{
    __shared__ unsigned short Ws[128][136];
    __shared__ unsigned short Ts[64][136];

    const int tid  = threadIdx.x;
    const int lane = tid & 63;
    const int wave = tid >> 6;
    const int quad = lane >> 4;
    const int l16  = lane & 15;
    const int row0 = blockIdx.x * 64 + wave * 16;

    stage_weight(G1t, Ws, tid);

    bf16x8 a[4];
    {
        const int row = row0 + l16;
        if (row < N) {
            const unsigned short* ap = Ab + (size_t)row * 128 + quad * 8;
            #pragma unroll
            for (int kc = 0; kc < 4; ++kc) a[kc] = *(const bf16x8*)(ap + kc * 32);
        } else {
            #pragma unroll
            for (int kc = 0; kc < 4; ++kc) a[kc] = zero_ab();
        }
    }
    __syncthreads();

    f32x4 acc[8];
    #pragma unroll
    for (int nt = 0; nt < 8; ++nt) acc[nt] = (f32x4){0.f, 0.f, 0.f, 0.f};
    #pragma unroll
    for (int nt = 0; nt < 8; ++nt) {
        const unsigned short* wp = &Ws[nt * 16 + l16][quad * 8];
        #pragma unroll
        for (int kc = 0; kc < 4; ++kc) {
            const bf16x8 b = *(const bf16x8*)(wp + kc * 32);
            acc[nt] = __builtin_amdgcn_mfma_f32_16x16x32_bf16(a[kc], b, acc[nt], 0, 0, 0);
        }
    }

    #pragma unroll
    for (int nt = 0; nt < 8; ++nt) {
        const int col = nt * 16 + l16;
        const float b1 = g_b1[col];
        #pragma unroll
        for (int reg = 0; reg < 4; ++reg) {
            float t = acc[nt][reg] + b1;
            t = LEAKY(t);
            Ts[wave * 16 + quad * 4 + reg][col] = f2bf(t);
        }
    }
    __syncthreads();
    stage_weight(G2t, Ws, tid);
    __syncthreads();

    bf16x8 a2[4];
    {
        const unsigned short* tp = &Ts[wave * 16 + l16][quad * 8];
        #pragma unroll
        for (int kc = 0; kc < 4; ++kc) a2[kc] = *(const bf16x8*)(tp + kc * 32);
    }

    f32x4 acc2[8];
    #pragma unroll
    for (int nt = 0; nt < 8; ++nt) acc2[nt] = (f32x4){0.f, 0.f, 0.f, 0.f};
    #pragma unroll
    for (int nt = 0; nt < 8; ++nt) {
        const unsigned short* wp = &Ws[nt * 16 + l16][quad * 8];
        #pragma unroll
        for (int kc = 0; kc < 4; ++kc) {
            const bf16x8 b = *(const bf16x8*)(wp + kc * 32);
            acc2[nt] = __builtin_amdgcn_mfma_f32_16x16x32_bf16(a2[kc], b, acc2[nt], 0, 0, 0);
        }
    }

    #pragma unroll
    for (int nt = 0; nt < 8; ++nt) {
        const int col = nt * 16 + l16;
        const float b2 = g_b2[col];
        #pragma unroll
        for (int reg = 0; reg < 4; ++reg) {
            const int grow = row0 + quad * 4 + reg;
            if (grow < N)
                out[(size_t)grow * 128 + col] =
                    acc2[nt][reg] + b2 + x[(size_t)grow * 128 + col];
        }
    }
}

// ---------------- launch ----------------
extern "C" void kernel_launch(void* const* d_in, const int* in_sizes, int n_in,
                              void* d_out, int out_size, void* d_ws, size_t ws_size,
                              hipStream_t stream) {
    const float* x    = (const float*)d_in[0];
    const float* pos  = (const float*)d_in[1];
    const int*   ei   = (const int*)d_in[2];
    const float* h_w1 = (const float*)d_in[3];
    const float* h_b1 = (const float*)d_in[4];
    const float* h_w2 = (const float*)d_in[5];
    const float* h_b2 = (const float*)d_in[6];
    const float* f_w  = (const float*)d_in[7];   // [131,128]
    const float* f_b  = (const float*)d_in[8];
    const float* g_w1 = (const float*)d_in[9];
    const float* g_b1 = (const float*)d_in[10];
    const float* g_w2 = (const float*)d_in[11];
    const float* g_b2 = (const float*)d_in[12];
    float* out = (float*)d_out;

    const int N = in_sizes[0] / 128;
    const int E = in_sizes[2] / 2;
    const int K = (N + 127) >> 7;          // coarse bins (128 dsts each), K <= KMAX

    // ws (~32 MB of 256 MB): deltap[N*3]f32 | Zb[N*128]u16 | bincnt[KMAX] |
    //   binstart[KMAX+1] | cursors[KMAX] | done | binned[E]u32 | srcs[E]u16 (fallback) |
    //   Wht/Wft/G1t/G2t [128*128]u16 each | Ab[N*128]u16
    float* deltap         = (float*)d_ws;
    unsigned short* Zb    = (unsigned short*)(deltap + (size_t)N * 3);
    int* bincnt           = (int*)(Zb + (size_t)N * 128);
    int* binstart         = bincnt + KMAX;
    int* cursors          = binstart + (KMAX + 1);
    int* done             = cursors + KMAX;
    unsigned int* binned  = (unsigned int*)(done + 1);
    unsigned short* srcs  = (unsigned short*)(binned + E);
    unsigned short* Wht   = srcs + (((size_t)E + 1) & ~(size_t)1);
    unsigned short* Wft   = Wht + 128 * 128;
    unsigned short* G1t   = Wft + 128 * 128;
    unsigned short* G2t   = G1t + 128 * 128;
    unsigned short* Ab    = G2t + 128 * 128;

    const int tile_blocks = (N + 63) / 64;
    const int sort_blocks = (E + S3_BATCH - 1) / S3_BATCH;

    prep_weights<<<128, 128, 0, stream>>>(h_w1, f_w, g_w1, g_w2, Wht, Wft, G1t, G2t,
                                          bincnt, done);

    fused_pre<<<HB + tile_blocks, 256, 0, stream>>>(
        x, pos, Wht, h_b1, h_w2, h_b2, Wft, f_b, f_w,
        deltap, Zb, ei, bincnt, binstart, cursors, done, E, K, N);

    binsort<<<sort_blocks, 512, 0, stream>>>(ei, cursors, binned, E, K);

    bin_csr_aggregate<<<K * 2, 512, 0, stream>>>(binned, binstart, deltap, Zb, f_w,
                                                 srcs, Ab, N);

    gemm_g<<<tile_blocks, 256, 0, stream>>>(Ab, G1t, g_b1, G2t, g_b2, x, out, N);
}